// Round 2
// baseline (4708.644 us; speedup 1.0000x reference)
//
#include <hip/hip_runtime.h>

#define N_B   64
#define N_T   1000
#define N_IN  80
#define N_REC 512
#define N_OUT 20
#define THR 1.0f

constexpr float ALPHA = 0.9512294245007140f; // exp(-1/20)
constexpr float KAPPA = 0.9512294245007140f;

// ---------------------------------------------------------------------------
// Kernel A: wT[j][r] = w_rec[r][j] (fp32), diagonal zeroed. 513 rows: row 512
// is all zeros (dummy target for spike-list padding). Also zeroes the
// cross-block mask-exchange flag area (must precede k_scan each launch/replay).
// ---------------------------------------------------------------------------
__global__ void k_transpose(const float* __restrict__ w_rec, float* __restrict__ wT,
                            unsigned long long* __restrict__ ex) {
    int i = blockIdx.x * blockDim.x + threadIdx.x;   // 0 .. 513*512-1
    if (i < 64 * 2 * 2 * 8) ex[i] = 0ull;            // 2048 u64 exchange slots
    if (i >= 513 * N_REC) return;
    int j = i >> 9;        // wT row  (source column), 0..512
    int r = i & 511;       // wT col  (source row)
    float v = 0.0f;
    if (j < N_REC && r != j) v = w_rec[r * N_REC + j];
    wT[i] = v;
}

// ---------------------------------------------------------------------------
// Kernel B: inj[(t-t0)*64 + b][r] = dot(x[b,t-1,:], w_in[r,:]) (masked) + noise[t,b,r]
// Noise load double-buffered one iteration ahead (hides ~900 cy HBM latency).
// ---------------------------------------------------------------------------
__global__ __launch_bounds__(512, 2) void k_inj(
    const float* __restrict__ x, const float* __restrict__ w_in,
    const float* __restrict__ noise, const int* __restrict__ seq,
    float* __restrict__ inj, int t0, int t1)
{
    const int r = threadIdx.x;
    float wreg[N_IN];
#pragma unroll
    for (int i = 0; i < N_IN; ++i) wreg[i] = w_in[r * N_IN + i];

    const int P = (t1 - t0) * N_B;
    const int stride = gridDim.x;

    auto nz = [&](int p) -> float {
        int pt = p >> 6, b = p & 63, t = t0 + pt;
        return __builtin_nontemporal_load(noise + ((size_t)t * N_B + b) * N_REC + r);
    };

    int p = blockIdx.x;
    float nxt = (p < P) ? nz(p) : 0.0f;
    for (; p < P; p += stride) {
        float acc = nxt;
        if (p + stride < P) nxt = nz(p + stride);
        int pt = p >> 6;
        int b  = p & 63;
        int t  = t0 + pt;
        if (t - 1 < seq[b]) {
            const float* xr = x + ((size_t)b * N_T + (t - 1)) * N_IN;
#pragma unroll
            for (int i = 0; i < N_IN; ++i) acc = fmaf(wreg[i], xr[i], acc);
        }
        inj[(size_t)p * N_REC + r] = acc;
    }
}

// ---------------------------------------------------------------------------
// Kernel C: sequential scan, COLUMN-SPLIT 2-way. Grid = 128: block (b, sh)
// owns batch b's columns [sh*256, sh*256+256). Per-CU gather traffic halves
// vs the 1-block/batch version (the measured bottleneck: ~64 B/cy/CU L2 BW).
// Per step:
//   A: spike gather for z(t-1): 8 waves x (npad/8) rows; each wave reads a
//      row's 1 KB half-slice as 64 lanes x float4. List indices via ONE
//      ds_read + readlane; rows double-buffered in batches of 4.
//      + dense vo partials for z(t-1) from zfp (w_out in VGPRs).
//   B: reduce 8 partials (stride-1 LDS), membrane update for our 256 neurons,
//      ballot -> own 4 mask words; [B2] thread 0 exchanges masks with the
//      partner block (agent-scope release/acquire, parity-double-buffered,
//      step-stamped flags) while wave 4 finalizes + stores vo(t-1).
//   C: full-mask spike list + zfp for z(t) (byte offsets, padded x32 with
//      the all-zero dummy row).
// Pairs (b, b+64) share an XCD under the bid%8 round-robin mapping (perf
// only; correctness is agent-scope). All 128 blocks co-resident -> no
// spin deadlock.
// ---------------------------------------------------------------------------
__global__ __launch_bounds__(512, 1) void k_scan(
    const float* __restrict__ wT, const float* __restrict__ inj,
    const float* __restrict__ w_out, float* __restrict__ out_vo,
    int t0, int t1,
    float* __restrict__ st_v, unsigned long long* __restrict__ st_zm,
    float* __restrict__ st_vo, unsigned long long* __restrict__ ex)
{
    const int bid  = blockIdx.x;
    const int b    = bid & 63;
    const int sh   = bid >> 6;       // column-half 0/1
    const int cbase = sh << 8;       // 0 or 256
    const int tid  = threadIdx.x;
    const int w    = tid >> 6;       // wave 0..7 == gather row-group
    const int lane = tid & 63;
    const unsigned long long lt = (1ull << lane) - 1ull;
    const int DUMMY = N_REC << 11;   // byte offset of the all-zero fp32 row

    __shared__ int lists[N_REC];                 // byte offsets (j<<11), padded
    __shared__ unsigned long long zm[8];         // full 512-bit mask (8 words)
    __shared__ float4 tmp_part[8][64];           // gather partials per wave
    __shared__ float tmp2[16][21];               // vo partials [s16][o], padded
    __shared__ alignas(16) float zfp[16 * 36];   // z floats, row s at s*36

    // w_out slice in registers: thread (o=tid>>4, s16=tid&15) owns
    // w_out[o][s16*32 .. s16*32+31]  (tid < 320)
    float wvo[32];
    {
        int o = tid >> 4, s16 = tid & 15;
        if (tid < 320) {
#pragma unroll
            for (int i = 0; i < 32; ++i)
                wvo[i] = w_out[(size_t)o * N_REC + s16 * 32 + i];
        } else {
#pragma unroll
            for (int i = 0; i < 32; ++i) wvo[i] = 0.0f;
        }
    }

    float v = 0.0f;      // membrane of neuron cbase+tid (tid<256)
    int zloc = 0;        // its previous spike
    float vo = 0.0f;     // vo state for output tid-256 (tid in [256,276))
    int npad = 0;

    if (t0 > 1) {
        if (tid < 256) v = st_v[(size_t)b * N_REC + cbase + tid];
        if (tid < 8) zm[tid] = st_zm[b * 8 + tid];
        if (tid >= 256 && tid < 256 + N_OUT) vo = st_vo[b * N_OUT + (tid - 256)];
        __syncthreads();
        if (tid < 256)
            zloc = (int)((zm[(cbase + tid) >> 6] >> (tid & 63)) & 1ull);
        // build spike list from the full mask
        int basep = 0, ntot = 0;
#pragma unroll
        for (int ww = 0; ww < 8; ++ww) {
            int c_ = __popcll(zm[ww]);
            if (ww < w) basep += c_;
            ntot += c_;
        }
        unsigned long long bmw = zm[w];
        if ((bmw >> lane) & 1ull) lists[basep + __popcll(bmw & lt)] = tid << 11;
        npad = (ntot + 31) & ~31;
        { int i = ntot + tid; if (i < npad) lists[i] = DUMMY; }
        __syncthreads();
    }

    // preload inj slice for t0 (nontemporal: don't evict wT from L2)
    float injn = 0.0f;
    if (tid < 256)
        injn = __builtin_nontemporal_load(
            inj + ((size_t)0 * N_B + b) * N_REC + cbase + tid);

    for (int t = t0; t < t1; ++t) {
        float injv = injn;

        // ---- Phase A: spike gather (our 256-col half) + vo partials ----
        float4 acc; acc.x = 0.0f; acc.y = 0.0f; acc.z = 0.0f; acc.w = 0.0f;
        {
            const int q = npad >> 3;             // rows per wave (multiple of 4)
            if (q > 0) {
                int jv = lists[w * q + lane];    // covers the wave's whole segment
                const char* wb = (const char*)wT + (sh << 10) + (lane << 4);
                const int nb = q >> 2;           // batches of 4 rows
                float4 vA[4];
#pragma unroll
                for (int u = 0; u < 4; ++u) {
                    int off = __builtin_amdgcn_readlane(jv, u);
                    vA[u] = *(const float4*)(wb + off);
                }
                for (int kb = 1; kb < nb; ++kb) {
                    float4 vB[4];
#pragma unroll
                    for (int u = 0; u < 4; ++u) {
                        int off = __builtin_amdgcn_readlane(jv, (kb << 2) + u);
                        vB[u] = *(const float4*)(wb + off);
                    }
#pragma unroll
                    for (int u = 0; u < 4; ++u) {
                        acc.x += vA[u].x; acc.y += vA[u].y;
                        acc.z += vA[u].z; acc.w += vA[u].w;
                        vA[u] = vB[u];
                    }
                }
#pragma unroll
                for (int u = 0; u < 4; ++u) {
                    acc.x += vA[u].x; acc.y += vA[u].y;
                    acc.z += vA[u].z; acc.w += vA[u].w;
                }
            }
        }
        // vo partials for z(t-1) (zfp written in C of t-1; overlaps vmcnt waits)
        if (t > t0 && tid < 320) {
            int o = tid >> 4, s16 = tid & 15;
            const float4* zp = (const float4*)(zfp + s16 * 36);
            float sa = 0.0f;
#pragma unroll
            for (int i = 0; i < 8; ++i) {
                float4 zv = zp[i];
                sa = fmaf(wvo[4 * i + 0], zv.x, sa);
                sa = fmaf(wvo[4 * i + 1], zv.y, sa);
                sa = fmaf(wvo[4 * i + 2], zv.z, sa);
                sa = fmaf(wvo[4 * i + 3], zv.w, sa);
            }
            tmp2[s16][o] = sa;
        }
        tmp_part[w][lane] = acc;

        // prefetch inj for t+1
        if (tid < 256 && t + 1 < t1)
            injn = __builtin_nontemporal_load(
                inj + ((size_t)(t + 1 - t0) * N_B + b) * N_REC + cbase + tid);

        __syncthreads();   // B1: tmp_part/tmp2 complete; zfp & lists consumed

        // ---- Phase B: reduce + membrane update + ballot ----
        if (tid < 256) {
            const float* tp = (const float*)tmp_part;
            float accn = injv;
#pragma unroll
            for (int gg = 0; gg < 8; ++gg) accn += tp[gg * 256 + tid];
            v = ALPHA * v + accn - (zloc ? THR : 0.0f);
            zloc = v > THR;
        }
        unsigned long long bm = __ballot(zloc);          // waves 4-7 give 0
        if (w < 4 && lane == 0) zm[sh * 4 + w] = bm;
        __syncthreads();   // B2: own mask words in LDS

        // exchange (wave 0, lane 0) || vo finalize (wave 4) in parallel
        if (tid == 0) {
            const int par = t & 1;
            unsigned long long* myslot = ex + (size_t)(((((b << 1) | sh) << 1) | par) * 8);
            unsigned long long* pslot  = ex + (size_t)(((((b << 1) | (1 - sh)) << 1) | par) * 8);
            unsigned long long w0 = zm[sh * 4 + 0], w1 = zm[sh * 4 + 1];
            unsigned long long w2 = zm[sh * 4 + 2], w3 = zm[sh * 4 + 3];
            __hip_atomic_store(myslot + 0, w0, __ATOMIC_RELAXED, __HIP_MEMORY_SCOPE_AGENT);
            __hip_atomic_store(myslot + 1, w1, __ATOMIC_RELAXED, __HIP_MEMORY_SCOPE_AGENT);
            __hip_atomic_store(myslot + 2, w2, __ATOMIC_RELAXED, __HIP_MEMORY_SCOPE_AGENT);
            __hip_atomic_store(myslot + 3, w3, __ATOMIC_RELAXED, __HIP_MEMORY_SCOPE_AGENT);
            __hip_atomic_store(myslot + 4, (unsigned long long)t,
                               __ATOMIC_RELEASE, __HIP_MEMORY_SCOPE_AGENT);
            while (__hip_atomic_load(pslot + 4, __ATOMIC_ACQUIRE,
                                     __HIP_MEMORY_SCOPE_AGENT) < (unsigned long long)t) {}
            zm[(1 - sh) * 4 + 0] = __hip_atomic_load(pslot + 0, __ATOMIC_RELAXED, __HIP_MEMORY_SCOPE_AGENT);
            zm[(1 - sh) * 4 + 1] = __hip_atomic_load(pslot + 1, __ATOMIC_RELAXED, __HIP_MEMORY_SCOPE_AGENT);
            zm[(1 - sh) * 4 + 2] = __hip_atomic_load(pslot + 2, __ATOMIC_RELAXED, __HIP_MEMORY_SCOPE_AGENT);
            zm[(1 - sh) * 4 + 3] = __hip_atomic_load(pslot + 3, __ATOMIC_RELAXED, __HIP_MEMORY_SCOPE_AGENT);
        } else if (tid >= 256 && tid < 256 + N_OUT && t > t0) {
            float sum = 0.0f;
#pragma unroll
            for (int ss = 0; ss < 16; ++ss) sum += tmp2[ss][tid - 256];
            vo = KAPPA * vo + sum;
            out_vo[((size_t)(t - 1) * N_B + b) * N_OUT + (tid - 256)] = vo;
        }
        __syncthreads();   // B3: full 8-word mask in zm

        // ---- Phase C: spike list + zfp for z(t) ----
        {
            int basep = 0, ntot = 0;
#pragma unroll
            for (int ww = 0; ww < 8; ++ww) {
                int c_ = __popcll(zm[ww]);
                if (ww < w) basep += c_;
                ntot += c_;
            }
            unsigned long long bmw = zm[w];
            if ((bmw >> lane) & 1ull) lists[basep + __popcll(bmw & lt)] = tid << 11;
            int npn = (ntot + 31) & ~31;
            { int i = ntot + tid; if (i < npn) lists[i] = DUMMY; }
            npad = npn;
            zfp[(tid >> 5) * 36 + (tid & 31)] =
                ((zm[tid >> 6] >> (tid & 63)) & 1ull) ? 1.0f : 0.0f;
        }
        __syncthreads();   // B4: list + zfp complete
    }

    // ---- tail: vo partials + finalize for z(t1-1) ----
    if (tid < 320) {
        int o = tid >> 4, s16 = tid & 15;
        const float4* zp = (const float4*)(zfp + s16 * 36);
        float sa = 0.0f;
#pragma unroll
        for (int i = 0; i < 8; ++i) {
            float4 zv = zp[i];
            sa = fmaf(wvo[4 * i + 0], zv.x, sa);
            sa = fmaf(wvo[4 * i + 1], zv.y, sa);
            sa = fmaf(wvo[4 * i + 2], zv.z, sa);
            sa = fmaf(wvo[4 * i + 3], zv.w, sa);
        }
        tmp2[s16][o] = sa;
    }
    __syncthreads();
    if (tid >= 256 && tid < 256 + N_OUT) {
        float sum = 0.0f;
#pragma unroll
        for (int ss = 0; ss < 16; ++ss) sum += tmp2[ss][tid - 256];
        vo = KAPPA * vo + sum;
        out_vo[((size_t)(t1 - 1) * N_B + b) * N_OUT + (tid - 256)] = vo;
        st_vo[b * N_OUT + (tid - 256)] = vo;
    }

    // checkpoint state for next chunk (duplicate identical writes are benign)
    if (tid < 256) st_v[(size_t)b * N_REC + cbase + tid] = v;
    if (tid < 8) st_zm[b * 8 + tid] = zm[tid];
}

// ---------------------------------------------------------------------------
// Kernel D: softmax over the 20 outputs; also writes the t=0 rows.
// ---------------------------------------------------------------------------
__global__ void k_softmax(const float* __restrict__ vo_seq,
                          float* __restrict__ out_sm,
                          float* __restrict__ out_vo0)
{
    int idx = blockIdx.x * blockDim.x + threadIdx.x;
    if (idx >= N_B * N_T) return;
    int b = idx / N_T;
    int t = idx - b * N_T;
    float vals[N_OUT];
    if (t == 0) {
#pragma unroll
        for (int o = 0; o < N_OUT; ++o) {
            vals[o] = 0.0f;
            out_vo0[(size_t)b * N_OUT + o] = 0.0f;   // vo[0] = zeros
        }
    } else {
#pragma unroll
        for (int o = 0; o < N_OUT; ++o)
            vals[o] = vo_seq[((size_t)t * N_B + b) * N_OUT + o];
    }
    float mx = vals[0];
#pragma unroll
    for (int o = 1; o < N_OUT; ++o) mx = fmaxf(mx, vals[o]);
    float s = 0.0f;
#pragma unroll
    for (int o = 0; o < N_OUT; ++o) { vals[o] = expf(vals[o] - mx); s += vals[o]; }
    float inv = 1.0f / s;
#pragma unroll
    for (int o = 0; o < N_OUT; ++o)
        out_sm[((size_t)b * N_T + t) * N_OUT + o] = vals[o] * inv;
}

// ---------------------------------------------------------------------------
extern "C" void kernel_launch(void* const* d_in, const int* in_sizes, int n_in,
                              void* d_out, int out_size, void* d_ws, size_t ws_size,
                              hipStream_t stream)
{
    (void)in_sizes; (void)n_in; (void)out_size;
    const float* x     = (const float*)d_in[0];
    const float* w_in  = (const float*)d_in[1];
    const float* w_rec = (const float*)d_in[2];
    const float* w_out = (const float*)d_in[3];
    const float* noise = (const float*)d_in[4];
    const int*   seq   = (const int*)d_in[5];

    float* out    = (float*)d_out;
    float* out_sm = out;                                   // (B,T,20)
    float* out_vo = out + (size_t)N_B * N_T * N_OUT;       // (T,B,20)

    char* ws = (char*)d_ws;
    float* wT = (float*)ws;
    size_t off = (size_t)513 * N_REC * sizeof(float);      // 513 rows (row 512 = zeros)
    off = (off + 255) & ~(size_t)255;
    float* st_v = (float*)(ws + off);                off += (size_t)N_B * N_REC * sizeof(float);
    unsigned long long* st_zm = (unsigned long long*)(ws + off); off += (size_t)N_B * 8 * sizeof(unsigned long long);
    float* st_vo = (float*)(ws + off);               off += (size_t)N_B * N_OUT * sizeof(float);
    off = (off + 255) & ~(size_t)255;
    unsigned long long* ex = (unsigned long long*)(ws + off);
    off += (size_t)64 * 2 * 2 * 8 * sizeof(unsigned long long);   // 16 KB exchange area
    off = (off + 255) & ~(size_t)255;
    float* inj = (float*)(ws + off);

    size_t avail = (ws_size > off) ? (ws_size - off) : 0;
    size_t step_bytes = (size_t)N_B * N_REC * sizeof(float);   // 128 KB per step
    long max_steps = (long)(avail / step_bytes);
    int tchunk = (int)((max_steps > (N_T - 1)) ? (N_T - 1) : max_steps);
    if (tchunk < 1) tchunk = 1;

    k_transpose<<<dim3((513 * N_REC + 255) / 256), dim3(256), 0, stream>>>(w_rec, wT, ex);

    for (int t0 = 1; t0 < N_T; t0 += tchunk) {
        int t1 = t0 + tchunk; if (t1 > N_T) t1 = N_T;
        k_inj<<<dim3(512), dim3(512), 0, stream>>>(x, w_in, noise, seq, inj, t0, t1);
        k_scan<<<dim3(2 * N_B), dim3(512), 0, stream>>>(wT, inj, w_out, out_vo,
                                                        t0, t1, st_v, st_zm, st_vo, ex);
    }

    k_softmax<<<dim3((N_B * N_T + 255) / 256), dim3(256), 0, stream>>>(out_vo, out_sm, out_vo);
}

// Round 3
// 2486.681 us; speedup vs baseline: 1.8935x; 1.8935x over previous
//
#include <hip/hip_runtime.h>

#define N_B   64
#define N_T   1000
#define N_IN  80
#define N_REC 512
#define N_OUT 20
#define THR 1.0f

constexpr float ALPHA = 0.9512294245007140f; // exp(-1/20)
constexpr float KAPPA = 0.9512294245007140f;

// ---------------------------------------------------------------------------
// Kernel A: wT[j][r] = w_rec[r][j] (fp32), diagonal zeroed. 513 rows: row 512
// is all zeros (dummy target for spike-list padding). Also zeroes the
// cross-block mask-exchange area (stamped-word protocol needs stamp<t0).
// ---------------------------------------------------------------------------
__global__ void k_transpose(const float* __restrict__ w_rec, float* __restrict__ wT,
                            unsigned long long* __restrict__ ex) {
    int i = blockIdx.x * blockDim.x + threadIdx.x;   // 0 .. 513*512-1
    if (i < 64 * 2 * 2 * 8) ex[i] = 0ull;            // 2048 u64 exchange slots
    if (i >= 513 * N_REC) return;
    int j = i >> 9;        // wT row  (source column), 0..512
    int r = i & 511;       // wT col  (source row)
    float v = 0.0f;
    if (j < N_REC && r != j) v = w_rec[r * N_REC + j];
    wT[i] = v;
}

// ---------------------------------------------------------------------------
// Kernel B: inj[(t-t0)*64 + b][r] = dot(x[b,t-1,:], w_in[r,:]) (masked) + noise[t,b,r]
// ---------------------------------------------------------------------------
__global__ __launch_bounds__(512, 2) void k_inj(
    const float* __restrict__ x, const float* __restrict__ w_in,
    const float* __restrict__ noise, const int* __restrict__ seq,
    float* __restrict__ inj, int t0, int t1)
{
    const int r = threadIdx.x;
    float wreg[N_IN];
#pragma unroll
    for (int i = 0; i < N_IN; ++i) wreg[i] = w_in[r * N_IN + i];

    const int P = (t1 - t0) * N_B;
    const int stride = gridDim.x;

    auto nz = [&](int p) -> float {
        int pt = p >> 6, b = p & 63, t = t0 + pt;
        return __builtin_nontemporal_load(noise + ((size_t)t * N_B + b) * N_REC + r);
    };

    int p = blockIdx.x;
    float nxt = (p < P) ? nz(p) : 0.0f;
    for (; p < P; p += stride) {
        float acc = nxt;
        if (p + stride < P) nxt = nz(p + stride);
        int pt = p >> 6;
        int b  = p & 63;
        int t  = t0 + pt;
        if (t - 1 < seq[b]) {
            const float* xr = x + ((size_t)b * N_T + (t - 1)) * N_IN;
#pragma unroll
            for (int i = 0; i < N_IN; ++i) acc = fmaf(wreg[i], xr[i], acc);
        }
        inj[(size_t)p * N_REC + r] = acc;
    }
}

// ---------------------------------------------------------------------------
// Kernel C: sequential scan, 2-way column split with OVERLAPPED mask exchange.
// Grid = 128: block (b, sh) owns batch b's columns [sh*256, sh*256+256).
//
// Exchange protocol (one IC round trip, fully hidden under the A1 gather):
//   - slot word = (stamp<<32)|mask_half; 8 words per (b,sh,parity).
//   - writer: 8x atomicExch fire-and-forget right after the ballot (phase B).
//   - reader: 8 lanes issue ONE speculative atomicAdd(p,0) at the top of A1,
//     check stamps after the gather; retry only if stale (rare).
//   - depth-2 parity ring; publish(t) happens-after consume(t-1) on both
//     sides, so slot reuse at t+2 can never overtake an unconsumed read.
//
// Gather is split by row source: A1 = rows from OWN half-mask (list built in
// phase C of the previous step, no exchange needed), A2 = rows from the
// partner half-mask (list built after the hidden poll). Rows 0..113 of the
// block's half-matrix are cached in LDS (114 KB) and served by the LDS pipe
// concurrently with the L2 stream.
// ---------------------------------------------------------------------------
__global__ __launch_bounds__(512, 1) void k_scan(
    const float* __restrict__ wT, const float* __restrict__ inj,
    const float* __restrict__ w_out, float* __restrict__ out_vo,
    int t0, int t1,
    float* __restrict__ st_v, unsigned long long* __restrict__ st_zm,
    float* __restrict__ st_vo, unsigned long long* __restrict__ ex)
{
    const int bid   = blockIdx.x;
    const int b     = bid & 63;
    const int sh    = bid >> 6;        // column-half 0/1
    const int cbase = sh << 8;
    const int pbase = (1 - sh) << 8;
    const int tid   = threadIdx.x;
    const int w     = tid >> 6;        // wave 0..7
    const int lane  = tid & 63;
    const unsigned long long lt = (1ull << lane) - 1ull;
    const int DUMMY = N_REC << 11;     // byte offset of the all-zero row
    constexpr int NCACHE = 114;                 // rows cached in LDS
    constexpr int CACHE_BYTES = NCACHE << 11;   // full-row byte offset cutoff

    __shared__ alignas(16) float ldsw[NCACHE * 256];   // 114 KB row cache (own half)
    __shared__ int lists_own[288];               // byte offsets (j<<11), padded x32
    __shared__ int lists_par[288];
    __shared__ unsigned long long zm_own[4];     // own mask words (for C + checkpoint)
    __shared__ unsigned int pzm32[8];            // partner mask as 8 u32 halves
    __shared__ float4 tmp_part[8][64];           // gather partials per wave
    __shared__ float tmp2[16][21];               // vo partials [s16][o], padded
    __shared__ alignas(16) float zfp[16 * 36];   // full z floats, row s at s*36

    // preload LDS row cache: rows 0..NCACHE-1, own 1KB column slice
    {
        float4* l4 = (float4*)ldsw;
        const char* src = (const char*)wT + (sh << 10);
        for (int i = tid; i < NCACHE * 64; i += 512) {
            int row = i >> 6, c4 = i & 63;
            l4[i] = *(const float4*)(src + ((size_t)row << 11) + (c4 << 4));
        }
    }

    // w_out slice in registers: thread (o=tid>>4, s16=tid&15) owns
    // w_out[o][s16*32 .. s16*32+31]  (tid < 320)
    float wvo[32];
    {
        int o = tid >> 4, s16 = tid & 15;
        if (tid < 320) {
#pragma unroll
            for (int i = 0; i < 32; ++i)
                wvo[i] = w_out[(size_t)o * N_REC + s16 * 32 + i];
        } else {
#pragma unroll
            for (int i = 0; i < 32; ++i) wvo[i] = 0.0f;
        }
    }

    float v = 0.0f;      // membrane of neuron cbase+tid (tid<256)
    int zloc = 0;        // its previous spike
    float vo = 0.0f;     // vo state for output tid-320 (tid in [320,340))
    int npad_own = 0, npad_par = 0;

    if (t0 == 1) {
        __syncthreads();   // ldsw visible
    } else {
        if (tid < 256) v = st_v[(size_t)b * N_REC + cbase + tid];
        if (tid < 4) zm_own[tid] = st_zm[b * 8 + sh * 4 + tid];
        if (tid >= 8 && tid < 16) {   // partner words as u32 halves
            int k = tid - 8;
            pzm32[k] = (unsigned int)(st_zm[b * 8 + (1 - sh) * 4 + (k >> 1)] >> ((k & 1) * 32));
        }
        if (tid >= 320 && tid < 320 + N_OUT) vo = st_vo[b * N_OUT + (tid - 320)];
        __syncthreads();
        // own list + zloc
        int ntot_o = 0, base_o = 0;
#pragma unroll
        for (int ww = 0; ww < 4; ++ww) {
            int c_ = __popcll(zm_own[ww]);
            ntot_o += c_;
            if (ww < (tid >> 6)) base_o += c_;
        }
        if (tid < 256) {
            unsigned long long mw = zm_own[tid >> 6];
            zloc = (int)((mw >> (tid & 63)) & 1ull);
            if (zloc) lists_own[base_o + __popcll(mw & lt)] = (cbase + tid) << 11;
        }
        npad_own = (ntot_o + 31) & ~31;
        { int i = ntot_o + tid; if (i < npad_own) lists_own[i] = DUMMY; }
        // partner list
        int ntot_p = 0, base_p = 0;
#pragma unroll
        for (int ww = 0; ww < 8; ++ww) {
            int c_ = __popc(pzm32[ww]);
            ntot_p += c_;
            if (ww < (tid >> 5)) base_p += c_;
        }
        if (tid < 256) {
            unsigned int wrd = pzm32[tid >> 5];
            base_p += __popc(wrd & ((1u << (tid & 31)) - 1u));
            if ((wrd >> (tid & 31)) & 1u)
                lists_par[base_p] = (pbase + tid) << 11;
        }
        npad_par = (ntot_p + 31) & ~31;
        { int i = ntot_p + tid; if (i < npad_par) lists_par[i] = DUMMY; }
        __syncthreads();
    }

    // mixed-source row gather: LDS-cached rows via ds_read, rest via L2
    const char* wbg = (const char*)wT + (sh << 10) + (lane << 4);
    const char* wbl = (const char*)ldsw + (lane << 4);
    auto gather = [&](const int* lst, int npadseg, float4& acc) {
        const int q = npadseg >> 3;          // rows per wave, multiple of 4
        if (q <= 0) return;
        int jv = lst[w * q + lane];          // one ds_read covers the segment
        for (int k = 0; k < q; k += 4) {
            float4 vv[4];
#pragma unroll
            for (int u = 0; u < 4; ++u) {
                int off = __builtin_amdgcn_readlane(jv, k + u);   // wave-uniform
                if (off < CACHE_BYTES) vv[u] = *(const float4*)(wbl + (off >> 1));
                else                   vv[u] = *(const float4*)(wbg + off);
            }
#pragma unroll
            for (int u = 0; u < 4; ++u) {
                acc.x += vv[u].x; acc.y += vv[u].y;
                acc.z += vv[u].z; acc.w += vv[u].w;
            }
        }
    };

    float injn = 0.0f;
    if (tid < 256)
        injn = __builtin_nontemporal_load(inj + ((size_t)0 * N_B + b) * N_REC + cbase + tid);

    for (int t = t0; t < t1; ++t) {
        float injv = injn;

        // speculative poll issue (partner mask of z(t-1)); result checked later
        unsigned long long spec = 0;
        unsigned long long* pex =
            ex + (size_t)((((b << 1) | (1 - sh)) << 1) | ((t - 1) & 1)) * 8;
        if (t > t0 && tid < 8) spec = atomicAdd(pex + tid, 0ull);

        // ---- A1: gather own-mask rows ----
        float4 acc; acc.x = 0.0f; acc.y = 0.0f; acc.z = 0.0f; acc.w = 0.0f;
        gather(lists_own, npad_own, acc);

        // prefetch inj for t+1
        if (tid < 256 && t + 1 < t1)
            injn = __builtin_nontemporal_load(
                inj + ((size_t)(t + 1 - t0) * N_B + b) * N_REC + cbase + tid);

        if (t > t0) {
            // poll completion (stamp == t-1); first try almost always hits
            if (tid < 8) {
                int guard = 0;
                while ((unsigned int)(spec >> 32) != (unsigned int)(t - 1) &&
                       ++guard < (1 << 22))
                    spec = atomicAdd(pex + tid, 0ull);
                pzm32[tid] = (unsigned int)spec;
            }
            __syncthreads();   // bar1: pzm32 visible
            // ---- A1.5: build partner list + zfp partner half ----
            int ntot_p = 0, base_p = 0;
#pragma unroll
            for (int ww = 0; ww < 8; ++ww) {
                int c_ = __popc(pzm32[ww]);
                ntot_p += c_;
                if (ww < (tid >> 5)) base_p += c_;
            }
            if (tid < 256) {
                unsigned int wrd = pzm32[tid >> 5];
                int bit = (wrd >> (tid & 31)) & 1;
                base_p += __popc(wrd & ((1u << (tid & 31)) - 1u));
                if (bit) lists_par[base_p] = (pbase + tid) << 11;
                int gi = pbase + tid;
                zfp[(gi >> 5) * 36 + (gi & 31)] = bit ? 1.0f : 0.0f;
            }
            npad_par = (ntot_p + 31) & ~31;
            { int i = ntot_p + tid; if (i < npad_par) lists_par[i] = DUMMY; }
            __syncthreads();   // bar2: lists_par + zfp ready
        }

        // ---- A2: gather partner-mask rows + vo partials for z(t-1) ----
        gather(lists_par, npad_par, acc);
        if (t > t0 && tid < 320) {
            int o = tid >> 4, s16 = tid & 15;
            const float4* zp = (const float4*)(zfp + s16 * 36);
            float sa = 0.0f;
#pragma unroll
            for (int i = 0; i < 8; ++i) {
                float4 zv = zp[i];
                sa = fmaf(wvo[4 * i + 0], zv.x, sa);
                sa = fmaf(wvo[4 * i + 1], zv.y, sa);
                sa = fmaf(wvo[4 * i + 2], zv.z, sa);
                sa = fmaf(wvo[4 * i + 3], zv.w, sa);
            }
            tmp2[s16][o] = sa;
        }
        tmp_part[w][lane] = acc;
        __syncthreads();   // bar3: partials complete

        // ---- B: reduce + membrane update + ballot + publish + vo finalize ----
        if (tid < 256) {
            const float* tp = (const float*)tmp_part;
            float accn = injv;
#pragma unroll
            for (int gg = 0; gg < 8; ++gg) accn += tp[gg * 256 + tid];
            v = ALPHA * v + accn - (zloc ? THR : 0.0f);
            zloc = v > THR;
        }
        unsigned long long bm = __ballot(zloc);      // waves 4-7 -> 0
        if (w < 4) {
            if (lane == 0) zm_own[w] = bm;
            if (lane < 2) {
                unsigned long long word =
                    ((unsigned long long)(unsigned int)t << 32) |
                    (unsigned long long)(unsigned int)(bm >> (lane * 32));
                atomicExch(ex + (size_t)((((b << 1) | sh) << 1) | (t & 1)) * 8 +
                           (w * 2 + lane), word);    // fire-and-forget
            }
        }
        if (t > t0 && tid >= 320 && tid < 320 + N_OUT) {
            int o = tid - 320;
            float sum = 0.0f;
#pragma unroll
            for (int ss = 0; ss < 16; ++ss) sum += tmp2[ss][o];
            vo = KAPPA * vo + sum;
            out_vo[((size_t)(t - 1) * N_B + b) * N_OUT + o] = vo;
        }
        __syncthreads();   // bar4: zm_own visible

        // ---- C: own spike list + zfp own half for z(t) ----
        {
            int ntot_o = 0, base_o = 0;
#pragma unroll
            for (int ww = 0; ww < 4; ++ww) {
                int c_ = __popcll(zm_own[ww]);
                ntot_o += c_;
                if (ww < (tid >> 6)) base_o += c_;
            }
            if (tid < 256) {
                if (zloc) lists_own[base_o + __popcll(bm & lt)] = (cbase + tid) << 11;
                int gi = cbase + tid;
                zfp[(gi >> 5) * 36 + (gi & 31)] = zloc ? 1.0f : 0.0f;
            }
            int npn = (ntot_o + 31) & ~31;
            { int i = ntot_o + tid; if (i < npn) lists_own[i] = DUMMY; }
            npad_own = npn;
        }
        __syncthreads();   // bar5: list_own ready for next A1
    }

    // ---- tail: poll partner mask of z(t1-1), vo partials + finalize ----
    {
        unsigned long long* pex =
            ex + (size_t)((((b << 1) | (1 - sh)) << 1) | ((t1 - 1) & 1)) * 8;
        if (tid < 8) {
            unsigned long long spec;
            int guard = 0;
            do { spec = atomicAdd(pex + tid, 0ull); }
            while ((unsigned int)(spec >> 32) != (unsigned int)(t1 - 1) &&
                   ++guard < (1 << 22));
            pzm32[tid] = (unsigned int)spec;
        }
        __syncthreads();
        if (tid < 256) {
            unsigned int wrd = pzm32[tid >> 5];
            int gi = pbase + tid;
            zfp[(gi >> 5) * 36 + (gi & 31)] = ((wrd >> (tid & 31)) & 1u) ? 1.0f : 0.0f;
        }
        __syncthreads();
    }
    if (tid < 320) {
        int o = tid >> 4, s16 = tid & 15;
        const float4* zp = (const float4*)(zfp + s16 * 36);
        float sa = 0.0f;
#pragma unroll
        for (int i = 0; i < 8; ++i) {
            float4 zv = zp[i];
            sa = fmaf(wvo[4 * i + 0], zv.x, sa);
            sa = fmaf(wvo[4 * i + 1], zv.y, sa);
            sa = fmaf(wvo[4 * i + 2], zv.z, sa);
            sa = fmaf(wvo[4 * i + 3], zv.w, sa);
        }
        tmp2[s16][o] = sa;
    }
    __syncthreads();
    if (tid >= 320 && tid < 320 + N_OUT) {
        int o = tid - 320;
        float sum = 0.0f;
#pragma unroll
        for (int ss = 0; ss < 16; ++ss) sum += tmp2[ss][o];
        vo = KAPPA * vo + sum;
        out_vo[((size_t)(t1 - 1) * N_B + b) * N_OUT + o] = vo;
        st_vo[b * N_OUT + o] = vo;
    }

    // checkpoint state for next chunk
    if (tid < 256) st_v[(size_t)b * N_REC + cbase + tid] = v;
    if (tid < 4) st_zm[b * 8 + sh * 4 + tid] = zm_own[tid];
}

// ---------------------------------------------------------------------------
// Kernel D: softmax over the 20 outputs; also writes the t=0 rows.
// ---------------------------------------------------------------------------
__global__ void k_softmax(const float* __restrict__ vo_seq,
                          float* __restrict__ out_sm,
                          float* __restrict__ out_vo0)
{
    int idx = blockIdx.x * blockDim.x + threadIdx.x;
    if (idx >= N_B * N_T) return;
    int b = idx / N_T;
    int t = idx - b * N_T;
    float vals[N_OUT];
    if (t == 0) {
#pragma unroll
        for (int o = 0; o < N_OUT; ++o) {
            vals[o] = 0.0f;
            out_vo0[(size_t)b * N_OUT + o] = 0.0f;   // vo[0] = zeros
        }
    } else {
#pragma unroll
        for (int o = 0; o < N_OUT; ++o)
            vals[o] = vo_seq[((size_t)t * N_B + b) * N_OUT + o];
    }
    float mx = vals[0];
#pragma unroll
    for (int o = 1; o < N_OUT; ++o) mx = fmaxf(mx, vals[o]);
    float s = 0.0f;
#pragma unroll
    for (int o = 0; o < N_OUT; ++o) { vals[o] = expf(vals[o] - mx); s += vals[o]; }
    float inv = 1.0f / s;
#pragma unroll
    for (int o = 0; o < N_OUT; ++o)
        out_sm[((size_t)b * N_T + t) * N_OUT + o] = vals[o] * inv;
}

// ---------------------------------------------------------------------------
extern "C" void kernel_launch(void* const* d_in, const int* in_sizes, int n_in,
                              void* d_out, int out_size, void* d_ws, size_t ws_size,
                              hipStream_t stream)
{
    (void)in_sizes; (void)n_in; (void)out_size;
    const float* x     = (const float*)d_in[0];
    const float* w_in  = (const float*)d_in[1];
    const float* w_rec = (const float*)d_in[2];
    const float* w_out = (const float*)d_in[3];
    const float* noise = (const float*)d_in[4];
    const int*   seq   = (const int*)d_in[5];

    float* out    = (float*)d_out;
    float* out_sm = out;                                   // (B,T,20)
    float* out_vo = out + (size_t)N_B * N_T * N_OUT;       // (T,B,20)

    char* ws = (char*)d_ws;
    float* wT = (float*)ws;
    size_t off = (size_t)513 * N_REC * sizeof(float);      // 513 rows (row 512 = zeros)
    off = (off + 255) & ~(size_t)255;
    float* st_v = (float*)(ws + off);                off += (size_t)N_B * N_REC * sizeof(float);
    unsigned long long* st_zm = (unsigned long long*)(ws + off); off += (size_t)N_B * 8 * sizeof(unsigned long long);
    float* st_vo = (float*)(ws + off);               off += (size_t)N_B * N_OUT * sizeof(float);
    off = (off + 255) & ~(size_t)255;
    unsigned long long* ex = (unsigned long long*)(ws + off);
    off += (size_t)64 * 2 * 2 * 8 * sizeof(unsigned long long);   // 16 KB exchange area
    off = (off + 255) & ~(size_t)255;
    float* inj = (float*)(ws + off);

    size_t avail = (ws_size > off) ? (ws_size - off) : 0;
    size_t step_bytes = (size_t)N_B * N_REC * sizeof(float);   // 128 KB per step
    long max_steps = (long)(avail / step_bytes);
    int tchunk = (int)((max_steps > (N_T - 1)) ? (N_T - 1) : max_steps);
    if (tchunk < 1) tchunk = 1;

    k_transpose<<<dim3((513 * N_REC + 255) / 256), dim3(256), 0, stream>>>(w_rec, wT, ex);

    for (int t0 = 1; t0 < N_T; t0 += tchunk) {
        int t1 = t0 + tchunk; if (t1 > N_T) t1 = N_T;
        k_inj<<<dim3(512), dim3(512), 0, stream>>>(x, w_in, noise, seq, inj, t0, t1);
        k_scan<<<dim3(2 * N_B), dim3(512), 0, stream>>>(wT, inj, w_out, out_vo,
                                                        t0, t1, st_v, st_zm, st_vo, ex);
    }

    k_softmax<<<dim3((N_B * N_T + 255) / 256), dim3(256), 0, stream>>>(out_vo, out_sm, out_vo);
}